// Round 11
// baseline (174.927 us; speedup 1.0000x reference)
//
#include <hip/hip_runtime.h>

// Problem constants (match reference)
static constexpr int NN   = 65536;   // total nodes
static constexpr int NPG  = 256;     // nodes per graph
static constexpr int NB   = 256;     // graphs (batch)
static constexpr int EMB  = 128;     // gcn emb dim
static constexpr int NOUT = 512;     // n_embd

static constexpr int NBIN = 256;     // partitions over dst>>8 (256 nodes each)
static constexpr int CAP  = 4608;    // bin capacity: mean 4096 edges, +8 sigma
static constexpr int VB   = 64;      // buildV rows carried by each of 4 stages

// Head GEMM tiling
static constexpr int BT = 8;         // batches per block
static constexpr int KS = 16;        // K-splits over the i axis
static constexpr int IC = NPG / KS;  // 16 i-iterations per block

// buildV for one i-row with T = NCG*128 threads:
// V4[i][j] = float4( sum_c W2[k][c]*W3[i*128+c][j], k=0..2, b2-row in .w )
// red must point to NCG*4*128 float4 of LDS.
template<int NCG>
__device__ __forceinline__ void buildV_row(int i, int tid,
        const float* __restrict__ W2, const float* __restrict__ b2,
        const float* __restrict__ W3, float4* __restrict__ V4,
        float4 (*red)[4][128]) {
    constexpr int CPG = 128 / NCG;       // c's per group
    constexpr int T   = NCG * 128;       // threads
    int j4 = tid & 127;                  // float4 column group
    int cg = tid >> 7;                   // 0..NCG-1
    const float4* w3 = (const float4*)(W3 + (size_t)i * EMB * NOUT)
                       + (size_t)cg * CPG * (NOUT/4) + j4;
    float4 a0 = {0,0,0,0}, a1 = {0,0,0,0}, a2 = {0,0,0,0}, a3 = {0,0,0,0};
    for (int c = 0; c < CPG; c++) {
        float4 v = w3[(size_t)c * (NOUT/4)];
        int cc = cg * CPG + c;
        float w0 = W2[0*EMB+cc], w1 = W2[1*EMB+cc], w2 = W2[2*EMB+cc], wb = b2[cc];
        a0.x += w0*v.x; a0.y += w0*v.y; a0.z += w0*v.z; a0.w += w0*v.w;
        a1.x += w1*v.x; a1.y += w1*v.y; a1.z += w1*v.z; a1.w += w1*v.w;
        a2.x += w2*v.x; a2.y += w2*v.y; a2.z += w2*v.z; a2.w += w2*v.w;
        a3.x += wb*v.x; a3.y += wb*v.y; a3.z += wb*v.z; a3.w += wb*v.w;
    }
    red[cg][0][j4] = a0;
    red[cg][1][j4] = a1;
    red[cg][2][j4] = a2;
    red[cg][3][j4] = a3;
    __syncthreads();
    for (int idx = tid; idx < 4 * 128; idx += T) {   // sum c-groups per (k, j4)
        int k = idx >> 7, jj = idx & 127;
        float4 s = red[0][k][jj];
#pragma unroll
        for (int g = 1; g < NCG; g++) {
            float4 v = red[g][k][jj];
            s.x += v.x; s.y += v.y; s.z += v.z; s.w += v.w;
        }
        red[0][k][jj] = s;
    }
    __syncthreads();
    for (int j = tid; j < NOUT; j += T) {            // assemble per-j float4 over k
        const float* r0 = (const float*)&red[0][0][j >> 2];
        const float* r1 = (const float*)&red[0][1][j >> 2];
        const float* r2 = (const float*)&red[0][2][j >> 2];
        const float* r3 = (const float*)&red[0][3][j >> 2];
        float4 o = { r0[j & 3], r1[j & 3], r2[j & 3], r3[j & 3] };
        V4[(size_t)i * NOUT + j] = o;
    }
}

// Blocks [0,VB): buildV rows 0..63. Blocks [VB, VB+256): radix-partition
// edges by dst>>8. packed edge = src | (dst&255)<<16
__global__ __launch_bounds__(1024)
void k_part(const int* __restrict__ src, const int* __restrict__ dst, int E,
            int* __restrict__ gbin, int* __restrict__ part,
            const float* __restrict__ W2, const float* __restrict__ b2,
            const float* __restrict__ W3, float4* __restrict__ V4) {
    union SH {
        struct { int hist[NBIN]; int loff[NBIN]; int base[NBIN]; int scanbuf[NBIN];
                 int stage[4096]; } part;                           // 20.5 KB
        float4 red[8][4][128];                                      // 64 KB
    };
    __shared__ SH sh;
    int tid = threadIdx.x;
    int bid = blockIdx.x;

    if (bid < VB) {
        buildV_row<8>(bid, tid, W2, b2, W3, V4, sh.red);
        return;
    }
    int pbid = bid - VB;
    int epb = (E + NBIN - 1) / NBIN;          // 4096 for E=1M
    int e0 = pbid * epb;
    int e1 = min(e0 + epb, E);
    if (tid < NBIN) sh.part.hist[tid] = 0;
    __syncthreads();

    int pk[4], bn[4], rk[4];
    int n = 0;
    int e = e0 + tid * 4;
    if (e + 4 <= e1) {
        int4 s4 = *(const int4*)(src + e);
        int4 d4 = *(const int4*)(dst + e);
        int ss[4] = {s4.x, s4.y, s4.z, s4.w};
        int dd[4] = {d4.x, d4.y, d4.z, d4.w};
#pragma unroll
        for (int k = 0; k < 4; k++) {
            pk[k] = ss[k] | ((dd[k] & 255) << 16);
            bn[k] = dd[k] >> 8;
            rk[k] = atomicAdd(&sh.part.hist[bn[k]], 1);
        }
        n = 4;
    } else {
        for (int k = 0; k < 4 && e + k < e1; k++) {
            int s = src[e+k], d = dst[e+k];
            pk[n] = s | ((d & 255) << 16);
            bn[n] = d >> 8;
            rk[n] = atomicAdd(&sh.part.hist[bn[n]], 1);
            n++;
        }
    }
    __syncthreads();

    if (tid < NBIN) sh.part.scanbuf[tid] = sh.part.hist[tid];
    __syncthreads();
    for (int off = 1; off < NBIN; off <<= 1) {
        int v = 0;
        if (tid < NBIN && tid >= off) v = sh.part.scanbuf[tid - off];
        __syncthreads();
        if (tid < NBIN) sh.part.scanbuf[tid] += v;
        __syncthreads();
    }
    if (tid < NBIN) {
        sh.part.loff[tid] = sh.part.scanbuf[tid] - sh.part.hist[tid];
        sh.part.base[tid] = atomicAdd(&gbin[tid], sh.part.hist[tid]);
    }
    __syncthreads();

    for (int k = 0; k < n; k++) sh.part.stage[sh.part.loff[bn[k]] + rk[k]] = pk[k];
    __syncthreads();

    int bin = tid >> 2;
    int cnt = sh.part.hist[bin], bs = sh.part.base[bin], lo = sh.part.loff[bin];
    for (int t = tid & 3; t < cnt; t += 4) {
        int gp = bs + t;
        if (gp < CAP) part[bin * CAP + gp] = sh.part.stage[lo + t];
    }
}

// Blocks [0,VB): buildV rows 64..127. Blocks [VB, VB+256): per-bin CSR
// (counting sort by dst) + degprep fused. 512 threads.
__global__ __launch_bounds__(512)
void k_csrV(const int* __restrict__ gbin, const int* __restrict__ part,
            const float* __restrict__ nodes,
            float* __restrict__ dinv, float4* __restrict__ y1,
            int* __restrict__ rs, unsigned short* __restrict__ srt,
            const float* __restrict__ W2, const float* __restrict__ b2,
            const float* __restrict__ W3, float4* __restrict__ V4) {
    union SH {
        struct { int pkst[CAP]; int hist[NPG]; int scanb[NPG]; int off_[NPG];
                 unsigned short stageS[CAP]; } csr;                 // 30.7 KB
        float4 red[4][4][128];                                      // 32 KB
    };
    __shared__ SH sh;
    int tid = threadIdx.x, bid = blockIdx.x;

    if (bid < VB) {
        buildV_row<4>(VB + bid, tid, W2, b2, W3, V4, sh.red);
        return;
    }
    int bin = bid - VB;
    if (tid < NPG) sh.csr.hist[tid] = 0;
    __syncthreads();
    int cnt = min(gbin[bin], CAP);
    const int* pp = part + (size_t)bin * CAP;
    for (int e = tid; e < cnt; e += 512) {
        int p = pp[e];
        sh.csr.pkst[e] = p;
        atomicAdd(&sh.csr.hist[(p >> 16) & 255], 1);
    }
    __syncthreads();
    if (tid < NPG) sh.csr.scanb[tid] = sh.csr.hist[tid];
    __syncthreads();
    for (int off = 1; off < NPG; off <<= 1) {
        int v = 0;
        if (tid < NPG && tid >= off) v = sh.csr.scanb[tid - off];
        __syncthreads();
        if (tid < NPG) sh.csr.scanb[tid] += v;
        __syncthreads();
    }
    if (tid < NPG) {
        int start = sh.csr.scanb[tid] - sh.csr.hist[tid];
        sh.csr.off_[tid] = start;
        int node = bin * NPG + tid;
        float di = rsqrtf((float)(sh.csr.hist[tid] + 1));   // +1 self-loop
        dinv[node] = di;
        y1[node] = make_float4(nodes[3*node+0] * di, nodes[3*node+1] * di,
                               nodes[3*node+2] * di, 0.f);
        rs[node] = start | (sh.csr.hist[tid] << 20);
    }
    __syncthreads();
    for (int e = tid; e < cnt; e += 512) {
        int p = sh.csr.pkst[e];
        int pos = atomicAdd(&sh.csr.off_[(p >> 16) & 255], 1);
        sh.csr.stageS[pos] = (unsigned short)(p & 0xFFFF);
    }
    __syncthreads();
    const unsigned int* so = (const unsigned int*)sh.csr.stageS;
    unsigned int* g = (unsigned int*)(srt + (size_t)bin * CAP);
    for (int t = tid; t < (cnt + 1) >> 1; t += 512) g[t] = so[t];
}

// Octet-per-node CSR gather (8 lanes/node; deg~16 -> 2 loads/lane).
__device__ __forceinline__ void agg_pass(int g, const int* __restrict__ rs,
                                         const unsigned short* __restrict__ srt,
                                         const float* __restrict__ dinv,
                                         const float* __restrict__ W1,
                                         const float* __restrict__ b1,
                                         const float4* __restrict__ yin,
                                         float4* __restrict__ yout, bool first) {
    int i = g >> 3, sub = g & 7;
    int rsd = rs[i];
    int start = rsd & 0xFFFFF, deg = rsd >> 20;
    const unsigned short* sp = srt + (size_t)(i >> 8) * CAP + start;
    float ax = 0.f, ay = 0.f, az = 0.f;
    for (int k = sub; k < deg; k += 8) {
        float4 v = yin[sp[k]];
        ax += v.x; ay += v.y; az += v.z;
    }
    ax += __shfl_xor(ax, 1); ay += __shfl_xor(ay, 1); az += __shfl_xor(az, 1);
    ax += __shfl_xor(ax, 2); ay += __shfl_xor(ay, 2); az += __shfl_xor(az, 2);
    ax += __shfl_xor(ax, 4); ay += __shfl_xor(ay, 4); az += __shfl_xor(az, 4);
    if (sub == 0) {
        float4 self = yin[i];
        float di = dinv[i];
        float a0 = (ax + self.x) * di, a1 = (ay + self.y) * di, a2 = (az + self.z) * di;
        if (first) {
            float h[3];
#pragma unroll
            for (int k = 0; k < 3; k++) {
                float t = a0 * W1[0*3+k] + a1 * W1[1*3+k] + a2 * W1[2*3+k] + b1[k];
                t = (t >= 0.f) ? t : 0.1f * t;
                h[k] = t * di;
            }
            yout[i] = make_float4(h[0], h[1], h[2], 0.f);
        } else {
            yout[i] = make_float4(a0, a1, a2, 0.f);
        }
    }
}

// Blocks [0,VB): buildV rows 128..191. Blocks [VB, VB+2048): gather round 1.
__global__ __launch_bounds__(256)
void k_agg1(const int* __restrict__ rs, const unsigned short* __restrict__ srt,
            const float* __restrict__ dinv, const float4* __restrict__ y1,
            const float* __restrict__ W1, const float* __restrict__ b1,
            float4* __restrict__ y2,
            const float* __restrict__ W2, const float* __restrict__ b2,
            const float* __restrict__ W3, float4* __restrict__ V4) {
    __shared__ float4 red[2][4][128];                               // 16 KB
    if (blockIdx.x < VB) {
        buildV_row<2>(2 * VB + blockIdx.x, threadIdx.x, W2, b2, W3, V4, red);
        return;
    }
    agg_pass((blockIdx.x - VB) * 256 + threadIdx.x, rs, srt, dinv, W1, b1,
             y1, y2, true);
}

// Blocks [0,VB): buildV rows 192..255. Blocks [VB, VB+2048): gather round 2.
__global__ __launch_bounds__(256)
void k_agg2(const int* __restrict__ rs, const unsigned short* __restrict__ srt,
            const float* __restrict__ dinv, const float4* __restrict__ y2,
            float4* __restrict__ agg2,
            const float* __restrict__ W2, const float* __restrict__ b2,
            const float* __restrict__ W3, float4* __restrict__ V4) {
    __shared__ float4 red[2][4][128];                               // 16 KB
    if (blockIdx.x < VB) {
        buildV_row<2>(3 * VB + blockIdx.x, threadIdx.x, W2, b2, W3, V4, red);
        return;
    }
    agg_pass((blockIdx.x - VB) * 256 + threadIdx.x, rs, srt, dinv, nullptr, nullptr,
             y2, agg2, false);
}

// Split-K head: one float4 V-load per (i,j).
__global__ void k_out_part(const float4* __restrict__ agg2, const float4* __restrict__ V4,
                           float* __restrict__ part) {
    __shared__ float4 a_s[BT * IC];
    int tid = threadIdx.x;
    int j  = blockIdx.x * 256 + tid;
    int b0 = blockIdx.y * BT;
    int i0 = blockIdx.z * IC;
    for (int idx = tid; idx < BT * IC; idx += 256) {
        int t = idx / IC, i = idx % IC;
        a_s[idx] = agg2[(size_t)(b0 + t) * NPG + i0 + i];
    }
    __syncthreads();

    float acc[BT];
#pragma unroll
    for (int t = 0; t < BT; t++) acc[t] = 0.f;

    const float4* vj = V4 + (size_t)i0 * NOUT + j;
    for (int i = 0; i < IC; i++) {
        float4 v = vj[(size_t)i * NOUT];
#pragma unroll
        for (int t = 0; t < BT; t++) {
            float4 a = a_s[t*IC + i];
            acc[t] += a.x * v.x + a.y * v.y + a.z * v.z + v.w;
        }
    }
#pragma unroll
    for (int t = 0; t < BT; t++)
        part[((size_t)blockIdx.z * NB + b0 + t) * NOUT + j] = acc[t];
}

// out = b3 + sum_s part[s]  (float4-vectorized)
__global__ void k_reduce(const float4* __restrict__ part4, const float4* __restrict__ b3_4,
                         float4* __restrict__ out4) {
    int idx = blockIdx.x * 256 + threadIdx.x;     // over NB*NOUT/4 = 32768
    int j4 = idx & (NOUT/4 - 1);
    float4 acc = b3_4[j4];
#pragma unroll
    for (int s = 0; s < KS; s++) {
        float4 v = part4[(size_t)s * (NB*NOUT/4) + idx];
        acc.x += v.x; acc.y += v.y; acc.z += v.z; acc.w += v.w;
    }
    out4[idx] = acc;
}

extern "C" void kernel_launch(void* const* d_in, const int* in_sizes, int n_in,
                              void* d_out, int out_size, void* d_ws, size_t ws_size,
                              hipStream_t stream) {
    const float* nodes = (const float*)d_in[0];
    const int*   ei    = (const int*)  d_in[1];
    const float* W1    = (const float*)d_in[2];
    const float* b1    = (const float*)d_in[3];
    const float* W2    = (const float*)d_in[4];
    const float* b2    = (const float*)d_in[5];
    const float* W3    = (const float*)d_in[6];
    const float* b3    = (const float*)d_in[7];

    const int E = in_sizes[1] / 2;
    const int* src = ei;
    const int* dst = ei + E;

    // Workspace layout (16B-aligned blocks)
    char* ws = (char*)d_ws;
    int*    gbin  = (int*)ws;                                 // 256 ints (pad 1 KB)
    float4* y1    = (float4*)(ws + 1024);                     // NN float4 (1 MB)
    float4* y2    = y1 + NN;                                  // 1 MB
    float4* agg2  = y2 + NN;                                  // 1 MB
    float4* V4    = agg2 + NN;                                // NPG*NOUT float4 (2 MB)
    float*  partO = (float*)(V4 + (size_t)NPG * NOUT);        // KS*NB*NOUT (8 MB)
    int*    partE = (int*)(partO + (size_t)KS * NB * NOUT);   // NBIN*CAP ints (4.7 MB)
    unsigned short* srt = (unsigned short*)(partE + (size_t)NBIN * CAP); // 2.3 MB
    int*    rs    = (int*)(srt + (size_t)NBIN * CAP);         // 256 KB
    float*  dinv  = (float*)(rs + NN);                        // 256 KB

    hipMemsetAsync(gbin, 0, NBIN * 4, stream);
    k_part    <<<VB + NBIN,      1024, 0, stream>>>(src, dst, E, gbin, partE,
                                                    W2, b2, W3, V4);
    k_csrV    <<<VB + NBIN,       512, 0, stream>>>(gbin, partE, nodes, dinv, y1,
                                                    rs, srt, W2, b2, W3, V4);
    k_agg1    <<<VB + NN*8/256,   256, 0, stream>>>(rs, srt, dinv, y1, W1, b1, y2,
                                                    W2, b2, W3, V4);
    k_agg2    <<<VB + NN*8/256,   256, 0, stream>>>(rs, srt, dinv, y2, agg2,
                                                    W2, b2, W3, V4);
    k_out_part<<<dim3(2, NB/BT, KS), 256, 0, stream>>>(agg2, V4, partO);
    k_reduce  <<<NB*NOUT/4/256,      256, 0, stream>>>((const float4*)partO,
                                                       (const float4*)b3, (float4*)d_out);
}

// Round 12
// 157.204 us; speedup vs baseline: 1.1127x; 1.1127x over previous
//
#include <hip/hip_runtime.h>

// Problem constants (match reference)
static constexpr int NN   = 65536;   // total nodes
static constexpr int NPG  = 256;     // nodes per graph
static constexpr int NB   = 256;     // graphs (batch)
static constexpr int EMB  = 128;     // gcn emb dim
static constexpr int NOUT = 512;     // n_embd

static constexpr int NBIN = 256;     // partitions over dst>>8 (256 nodes each)
static constexpr int CAP  = 4608;    // bin capacity: mean 4096 edges, +8 sigma
static constexpr int SCAP = CAP + 256; // sorted capacity incl. even-padding holes

// Head GEMM tiling
static constexpr int BT = 8;         // batches per block
static constexpr int KS = 16;        // K-splits over the i axis
static constexpr int IC = NPG / KS;  // 16 i-iterations per block

// Fused partition (blocks 0..255) + buildV (blocks 256..511, 1 V-row each,
// float4 W3 loads). V4[i][j] = float4( sum_c W2[k][c]*W3[i*128+c][j], k=0..2,
// b2-row in .w ). packed edge = src | (dst&255)<<16
__global__ __launch_bounds__(1024)
void k_partV(const int* __restrict__ src, const int* __restrict__ dst, int E,
             int* __restrict__ gbin, int* __restrict__ part,
             const float* __restrict__ W2, const float* __restrict__ b2,
             const float* __restrict__ W3, float4* __restrict__ V4) {
    union SH {
        struct { int hist[NBIN]; int loff[NBIN]; int base[NBIN]; int scanbuf[NBIN];
                 int stage[4096]; } part;                           // 20.5 KB
        float4 red[8][4][128];                                      // 64 KB
    };
    __shared__ SH sh;
    int tid = threadIdx.x;
    int bid = blockIdx.x;

    if (bid >= NBIN) {
        // ---- buildV role: one i-row, float4 loads, 8 c-groups of 16 ----
        int i  = bid - NBIN;
        int j4 = tid & 127;
        int cg = tid >> 7;
        const float4* w3 = (const float4*)(W3 + (size_t)i * EMB * NOUT)
                           + (size_t)cg * 16 * (NOUT/4) + j4;
        float4 a0 = {0,0,0,0}, a1 = {0,0,0,0}, a2 = {0,0,0,0}, a3 = {0,0,0,0};
        for (int c = 0; c < 16; c++) {
            float4 v = w3[(size_t)c * (NOUT/4)];
            int cc = cg*16 + c;
            float w0 = W2[0*EMB+cc], w1 = W2[1*EMB+cc], w2 = W2[2*EMB+cc], wb = b2[cc];
            a0.x += w0*v.x; a0.y += w0*v.y; a0.z += w0*v.z; a0.w += w0*v.w;
            a1.x += w1*v.x; a1.y += w1*v.y; a1.z += w1*v.z; a1.w += w1*v.w;
            a2.x += w2*v.x; a2.y += w2*v.y; a2.z += w2*v.z; a2.w += w2*v.w;
            a3.x += wb*v.x; a3.y += wb*v.y; a3.z += wb*v.z; a3.w += wb*v.w;
        }
        sh.red[cg][0][j4] = a0;
        sh.red[cg][1][j4] = a1;
        sh.red[cg][2][j4] = a2;
        sh.red[cg][3][j4] = a3;
        __syncthreads();
        if (tid < 512) {
            int k = tid >> 7, jj = tid & 127;
            float4 s = sh.red[0][k][jj];
#pragma unroll
            for (int g = 1; g < 8; g++) {
                float4 v = sh.red[g][k][jj];
                s.x += v.x; s.y += v.y; s.z += v.z; s.w += v.w;
            }
            sh.red[0][k][jj] = s;
        }
        __syncthreads();
        if (tid < NOUT) {
            int j = tid;
            const float* r0 = (const float*)&sh.red[0][0][j >> 2];
            const float* r1 = (const float*)&sh.red[0][1][j >> 2];
            const float* r2 = (const float*)&sh.red[0][2][j >> 2];
            const float* r3 = (const float*)&sh.red[0][3][j >> 2];
            float4 o = { r0[j & 3], r1[j & 3], r2[j & 3], r3[j & 3] };
            V4[(size_t)i * NOUT + j] = o;
        }
        return;
    }
    // ---- partition role: radix by dst>>8, LDS count+rank, coalesced out ----
    int epb = (E + NBIN - 1) / NBIN;          // 4096 for E=1M
    int e0 = bid * epb;
    int e1 = min(e0 + epb, E);
    if (tid < NBIN) sh.part.hist[tid] = 0;
    __syncthreads();

    int pk[4], bn[4], rk[4];
    int n = 0;
    int e = e0 + tid * 4;
    if (e + 4 <= e1) {
        int4 s4 = *(const int4*)(src + e);
        int4 d4 = *(const int4*)(dst + e);
        int ss[4] = {s4.x, s4.y, s4.z, s4.w};
        int dd[4] = {d4.x, d4.y, d4.z, d4.w};
#pragma unroll
        for (int k = 0; k < 4; k++) {
            pk[k] = ss[k] | ((dd[k] & 255) << 16);
            bn[k] = dd[k] >> 8;
            rk[k] = atomicAdd(&sh.part.hist[bn[k]], 1);
        }
        n = 4;
    } else {
        for (int k = 0; k < 4 && e + k < e1; k++) {
            int s = src[e+k], d = dst[e+k];
            pk[n] = s | ((d & 255) << 16);
            bn[n] = d >> 8;
            rk[n] = atomicAdd(&sh.part.hist[bn[n]], 1);
            n++;
        }
    }
    __syncthreads();

    if (tid < NBIN) sh.part.scanbuf[tid] = sh.part.hist[tid];
    __syncthreads();
    for (int off = 1; off < NBIN; off <<= 1) {
        int v = 0;
        if (tid < NBIN && tid >= off) v = sh.part.scanbuf[tid - off];
        __syncthreads();
        if (tid < NBIN) sh.part.scanbuf[tid] += v;
        __syncthreads();
    }
    if (tid < NBIN) {
        sh.part.loff[tid] = sh.part.scanbuf[tid] - sh.part.hist[tid];
        sh.part.base[tid] = atomicAdd(&gbin[tid], sh.part.hist[tid]);
    }
    __syncthreads();

    for (int k = 0; k < n; k++) sh.part.stage[sh.part.loff[bn[k]] + rk[k]] = pk[k];
    __syncthreads();

    int bin = tid >> 2;
    int cnt = sh.part.hist[bin], bs = sh.part.base[bin], lo = sh.part.loff[bin];
    for (int t = tid & 3; t < cnt; t += 4) {
        int gp = bs + t;
        if (gp < CAP) part[bin * CAP + gp] = sh.part.stage[lo + t];
    }
}

// Per-bin CSR build (counting sort by dst) + degprep fused. 512 threads.
// Node starts even-padded so neighbor lists are uint-aligned for the gathers.
// Scan over 256 entries via 64-wide wave scan + cross-wave fixup (1 barrier).
__global__ __launch_bounds__(512)
void k_csr(const int* __restrict__ gbin, const int* __restrict__ part,
           const float* __restrict__ nodes,
           float* __restrict__ dinv, float4* __restrict__ y1,
           int* __restrict__ rs, unsigned short* __restrict__ srt) {
    __shared__ int pkst[CAP];
    __shared__ int hist[NPG], off_[NPG];
    __shared__ int wtot[4];
    __shared__ unsigned short stageS[SCAP];
    int tid = threadIdx.x, bin = blockIdx.x;
    if (tid < NPG) hist[tid] = 0;
    __syncthreads();
    int cnt = min(gbin[bin], CAP);
    const int* pp = part + (size_t)bin * CAP;
    for (int e = tid; e < cnt; e += 512) {
        int p = pp[e];
        pkst[e] = p;
        atomicAdd(&hist[(p >> 16) & 255], 1);
    }
    __syncthreads();

    // wave-scan of even-padded counts
    int h = 0, v = 0;
    if (tid < NPG) { h = hist[tid]; v = (h + 1) & ~1; }
    int lane = tid & 63;
#pragma unroll
    for (int off = 1; off < 64; off <<= 1) {
        int t = __shfl_up(v, off, 64);
        if (tid < NPG && lane >= off) v += t;
    }
    if (tid < NPG && lane == 63) wtot[tid >> 6] = v;
    __syncthreads();
    if (tid < NPG) {
        int wv = tid >> 6;
        int offs = 0;
#pragma unroll
        for (int w = 0; w < 3; w++) if (w < wv) offs += wtot[w];
        int start = v + offs - ((h + 1) & ~1);     // exclusive even-padded start
        off_[tid] = start;
        int node = bin * NPG + tid;
        float di = rsqrtf((float)(h + 1));          // +1 self-loop
        dinv[node] = di;
        y1[node] = make_float4(nodes[3*node+0] * di, nodes[3*node+1] * di,
                               nodes[3*node+2] * di, 0.f);
        rs[node] = start | (h << 20);
    }
    __syncthreads();
    for (int e = tid; e < cnt; e += 512) {
        int p = pkst[e];
        int pos = atomicAdd(&off_[(p >> 16) & 255], 1);
        stageS[pos] = (unsigned short)(p & 0xFFFF);
    }
    __syncthreads();
    int tot = wtot[0] + wtot[1] + wtot[2] + wtot[3];   // even
    const unsigned int* so = (const unsigned int*)stageS;
    unsigned int* g = (unsigned int*)(srt + (size_t)bin * SCAP);
    for (int t = tid; t < (tot >> 1); t += 512) g[t] = so[t];
}

// Octet-per-node CSR gather: one coalesced uint = 2 neighbor ids per lane,
// both y-gathers issue independently (1 dependent round instead of 2).
__device__ __forceinline__ void agg_pass(int g, const int* __restrict__ rs,
                                         const unsigned short* __restrict__ srt,
                                         const float* __restrict__ dinv,
                                         const float* __restrict__ W1,
                                         const float* __restrict__ b1,
                                         const float4* __restrict__ yin,
                                         float4* __restrict__ yout, bool first) {
    int i = g >> 3, sub = g & 7;
    int rsd = rs[i];
    int start = rsd & 0xFFFFF, deg = rsd >> 20;
    const unsigned int* spw = (const unsigned int*)(srt + (size_t)(i >> 8) * SCAP + start);
    int npairs = (deg + 1) >> 1;
    float ax = 0.f, ay = 0.f, az = 0.f;
    for (int w = sub; w < npairs; w += 8) {
        unsigned int u = spw[w];
        float4 v0 = yin[u & 0xFFFF];
        ax += v0.x; ay += v0.y; az += v0.z;
        if (2*w + 1 < deg) {
            float4 v1 = yin[u >> 16];
            ax += v1.x; ay += v1.y; az += v1.z;
        }
    }
    ax += __shfl_xor(ax, 1); ay += __shfl_xor(ay, 1); az += __shfl_xor(az, 1);
    ax += __shfl_xor(ax, 2); ay += __shfl_xor(ay, 2); az += __shfl_xor(az, 2);
    ax += __shfl_xor(ax, 4); ay += __shfl_xor(ay, 4); az += __shfl_xor(az, 4);
    if (sub == 0) {
        float4 self = yin[i];
        float di = dinv[i];
        float a0 = (ax + self.x) * di, a1 = (ay + self.y) * di, a2 = (az + self.z) * di;
        if (first) {
            float h[3];
#pragma unroll
            for (int k = 0; k < 3; k++) {
                float t = a0 * W1[0*3+k] + a1 * W1[1*3+k] + a2 * W1[2*3+k] + b1[k];
                t = (t >= 0.f) ? t : 0.1f * t;
                h[k] = t * di;
            }
            yout[i] = make_float4(h[0], h[1], h[2], 0.f);
        } else {
            yout[i] = make_float4(a0, a1, a2, 0.f);
        }
    }
}

__global__ void k_agg1(const int* __restrict__ rs, const unsigned short* __restrict__ srt,
                       const float* __restrict__ dinv, const float4* __restrict__ y1,
                       const float* __restrict__ W1, const float* __restrict__ b1,
                       float4* __restrict__ y2) {
    agg_pass(blockIdx.x * 256 + threadIdx.x, rs, srt, dinv, W1, b1, y1, y2, true);
}

__global__ void k_agg2(const int* __restrict__ rs, const unsigned short* __restrict__ srt,
                       const float* __restrict__ dinv, const float4* __restrict__ y2,
                       float4* __restrict__ agg2) {
    agg_pass(blockIdx.x * 256 + threadIdx.x, rs, srt, dinv, nullptr, nullptr,
             y2, agg2, false);
}

// Split-K head: one float4 V-load per (i,j).
__global__ void k_out_part(const float4* __restrict__ agg2, const float4* __restrict__ V4,
                           float* __restrict__ part) {
    __shared__ float4 a_s[BT * IC];
    int tid = threadIdx.x;
    int j  = blockIdx.x * 256 + tid;
    int b0 = blockIdx.y * BT;
    int i0 = blockIdx.z * IC;
    for (int idx = tid; idx < BT * IC; idx += 256) {
        int t = idx / IC, i = idx % IC;
        a_s[idx] = agg2[(size_t)(b0 + t) * NPG + i0 + i];
    }
    __syncthreads();

    float acc[BT];
#pragma unroll
    for (int t = 0; t < BT; t++) acc[t] = 0.f;

    const float4* vj = V4 + (size_t)i0 * NOUT + j;
    for (int i = 0; i < IC; i++) {
        float4 v = vj[(size_t)i * NOUT];
#pragma unroll
        for (int t = 0; t < BT; t++) {
            float4 a = a_s[t*IC + i];
            acc[t] += a.x * v.x + a.y * v.y + a.z * v.z + v.w;
        }
    }
#pragma unroll
    for (int t = 0; t < BT; t++)
        part[((size_t)blockIdx.z * NB + b0 + t) * NOUT + j] = acc[t];
}

// out = b3 + sum_s part[s]  (float4-vectorized)
__global__ void k_reduce(const float4* __restrict__ part4, const float4* __restrict__ b3_4,
                         float4* __restrict__ out4) {
    int idx = blockIdx.x * 256 + threadIdx.x;     // over NB*NOUT/4 = 32768
    int j4 = idx & (NOUT/4 - 1);
    float4 acc = b3_4[j4];
#pragma unroll
    for (int s = 0; s < KS; s++) {
        float4 v = part4[(size_t)s * (NB*NOUT/4) + idx];
        acc.x += v.x; acc.y += v.y; acc.z += v.z; acc.w += v.w;
    }
    out4[idx] = acc;
}

extern "C" void kernel_launch(void* const* d_in, const int* in_sizes, int n_in,
                              void* d_out, int out_size, void* d_ws, size_t ws_size,
                              hipStream_t stream) {
    const float* nodes = (const float*)d_in[0];
    const int*   ei    = (const int*)  d_in[1];
    const float* W1    = (const float*)d_in[2];
    const float* b1    = (const float*)d_in[3];
    const float* W2    = (const float*)d_in[4];
    const float* b2    = (const float*)d_in[5];
    const float* W3    = (const float*)d_in[6];
    const float* b3    = (const float*)d_in[7];

    const int E = in_sizes[1] / 2;
    const int* src = ei;
    const int* dst = ei + E;

    // Workspace layout (16B-aligned blocks)
    char* ws = (char*)d_ws;
    int*    gbin  = (int*)ws;                                 // 256 ints (pad 1 KB)
    float4* y1    = (float4*)(ws + 1024);                     // NN float4 (1 MB)
    float4* y2    = y1 + NN;                                  // 1 MB
    float4* agg2  = y2 + NN;                                  // 1 MB
    float4* V4    = agg2 + NN;                                // NPG*NOUT float4 (2 MB)
    float*  partO = (float*)(V4 + (size_t)NPG * NOUT);        // KS*NB*NOUT (8 MB)
    int*    partE = (int*)(partO + (size_t)KS * NB * NOUT);   // NBIN*CAP ints (4.7 MB)
    unsigned short* srt = (unsigned short*)(partE + (size_t)NBIN * CAP); // 2.5 MB
    int*    rs    = (int*)(srt + (size_t)NBIN * SCAP);        // 256 KB
    float*  dinv  = (float*)(rs + NN);                        // 256 KB

    hipMemsetAsync(gbin, 0, NBIN * 4, stream);
    k_partV   <<<2*NBIN, 1024, 0, stream>>>(src, dst, E, gbin, partE, W2, b2, W3, V4);
    k_csr     <<<NBIN,    512, 0, stream>>>(gbin, partE, nodes, dinv, y1, rs, srt);
    k_agg1    <<<NN*8/256, 256, 0, stream>>>(rs, srt, dinv, y1, W1, b1, y2);
    k_agg2    <<<NN*8/256, 256, 0, stream>>>(rs, srt, dinv, y2, agg2);
    k_out_part<<<dim3(2, NB/BT, KS), 256, 0, stream>>>(agg2, V4, partO);
    k_reduce  <<<NB*NOUT/4/256,      256, 0, stream>>>((const float4*)partO,
                                                       (const float4*)b3, (float4*)d_out);
}